// Round 3
// baseline (434.648 us; speedup 1.0000x reference)
//
#include <hip/hip_runtime.h>
#include <stdint.h>

#define T_LEN 8192
#define C_LEN 64
#define OUT_LEN 8

// Kernel A: per row (b,t): pred = argmax_c x[b,t,c] (ties -> lowest c),
// conf = 1 / sum_c exp(x[b,t,c] - max_c) == max of softmax.
// 16 lanes/row, float4 per lane (1 KB per wave, coalesced).
// Measured R2: 45.8 us/launch vs 42 us BW floor (264 MB @ 6.3 TB/s) -> ~91%
// of achievable HBM BW. DO NOT CHURN; kept byte-identical for decomposition.
__global__ __launch_bounds__(256) void softmax_stats_kernel(
    const float* __restrict__ x, float* __restrict__ conf,
    int* __restrict__ pred, int nrows)
{
    const int tid  = threadIdx.x;
    const int wave = tid >> 6;
    const int lane = tid & 63;
    const int rw   = lane >> 4;   // row-within-wave (0..3)
    const int sub  = lane & 15;   // 16 lanes per row
    const long long row = (long long)blockIdx.x * 16 + wave * 4 + rw;
    if (row >= nrows) return;

    const float4 v = ((const float4*)(x + row * C_LEN))[sub];

    // local argmax over 4 elems, strict > keeps lowest index
    float m = v.x; int mi = sub * 4;
    if (v.y > m) { m = v.y; mi = sub * 4 + 1; }
    if (v.z > m) { m = v.z; mi = sub * 4 + 2; }
    if (v.w > m) { m = v.w; mi = sub * 4 + 3; }

    // sign-corrected monotone encoding of float bits
    const unsigned int s0 = __float_as_uint(m);
    const unsigned int u0 = (s0 & 0x80000000u) ? ~s0 : (s0 | 0x80000000u);
    unsigned long long key =
        ((unsigned long long)u0 << 32) | (unsigned int)~mi;

    #pragma unroll
    for (int off = 8; off >= 1; off >>= 1) {
        const unsigned long long o = __shfl_xor(key, off);
        if (o > key) key = o;     // tie in value -> larger ~mi -> smaller mi
    }

    const unsigned int uu = (unsigned int)(key >> 32);
    const float M = __uint_as_float(
        (uu & 0x80000000u) ? (uu ^ 0x80000000u) : ~uu);

    // native exp: v_mul + v_exp_f32 (args are <= 0, no range issues)
    float s = __expf(v.x - M) + __expf(v.y - M)
            + __expf(v.z - M) + __expf(v.w - M);
    #pragma unroll
    for (int off = 8; off >= 1; off >>= 1) s += __shfl_xor(s, off);

    if (sub == 0) {
        conf[row] = 1.0f / s;
        pred[row] = (int)~(unsigned int)(key & 0xffffffffu);
    }
}

// Kernel B: one block per batch sample. RLE + voted-confidence top-8.
// Kept byte-identical to R2 for the decomposition experiment.
__global__ __launch_bounds__(256) void topk_kernel(
    const float* __restrict__ conf, const int* __restrict__ pred,
    float* __restrict__ out)
{
    __shared__ short pred_s[T_LEN];                 // 16 KB
    __shared__ float voted_s[T_LEN];                // 32 KB
    __shared__ unsigned long long wkey[4];
    __shared__ int   dirty;                         // -1 = all rescan
    __shared__ float outbuf[OUT_LEN];

    const int b    = blockIdx.x;
    const int tid  = threadIdx.x;
    const int lane = tid & 63, wave = tid >> 6;
    const int* __restrict__   pb = pred + (long long)b * T_LEN;
    const float* __restrict__ cb = conf + (long long)b * T_LEN;

    // vectorized pred load: int4 -> 4 shorts
    for (int i = tid; i < T_LEN / 4; i += 256) {
        const int4 p4 = ((const int4*)pb)[i];
        short4 q; q.x = (short)p4.x; q.y = (short)p4.y;
        q.z = (short)p4.z; q.w = (short)p4.w;
        *(short4*)&pred_s[4 * i] = q;
    }
    if (tid == 0) dirty = -1;
    __syncthreads();

    // voted confidence at run starts; 0 elsewhere (real voted >= 1/64 > 0)
    for (int t = tid; t < T_LEN; t += 256) {
        const short p = pred_s[t];
        const bool start = (t == 0) || (pred_s[t - 1] != p);
        float v = 0.0f;
        if (start) {
            int len = 1;
            while (t + len < T_LEN && pred_s[t + len] == p) ++len;
            v = cb[t] * (float)len;   // conf at run START times run length
        }
        voted_s[t] = v;
    }
    __syncthreads();

    // 8 rounds of block argmax over keys (float bits | ~t): float bits are
    // order-preserving for v >= 0; ~t = lower-index tie-break (lax.top_k).
    for (int r = 0; r < OUT_LEN; ++r) {
        if (dirty == -1 || dirty == wave) {
            unsigned long long best = 0ull;
            const int base = wave * (T_LEN / 4);
            #pragma unroll 4
            for (int k = 0; k < T_LEN / 4 / 64; ++k) {
                const int t = base + k * 64 + lane;
                const unsigned long long key =
                    ((unsigned long long)__float_as_uint(voted_s[t]) << 32)
                    | (unsigned int)(~t);
                if (key > best) best = key;
            }
            #pragma unroll
            for (int off = 32; off >= 1; off >>= 1) {
                const unsigned long long o = __shfl_xor(best, off);
                if (o > best) best = o;
            }
            if (lane == 0) wkey[wave] = best;
        }
        __syncthreads();
        if (tid == 0) {
            unsigned long long bb = wkey[0];
            #pragma unroll
            for (int w = 1; w < 4; ++w) if (wkey[w] > bb) bb = wkey[w];
            const unsigned int widx = ~(unsigned int)(bb & 0xffffffffu);
            const float v = __uint_as_float((unsigned int)(bb >> 32));
            float ov = 0.0f;                        // pad-with-0 path
            if (v > 0.0f) {
                ov = (float)pred_s[widx];
                voted_s[widx] = 0.0f;
                dirty = (int)(widx / (T_LEN / 4));  // that wave rescans
            } else {
                dirty = 4;                          // nobody rescans
            }
            outbuf[r] = ov;
        }
        __syncthreads();
    }
    if (tid < OUT_LEN) out[b * OUT_LEN + tid] = outbuf[tid];
}

extern "C" void kernel_launch(void* const* d_in, const int* in_sizes, int n_in,
                              void* d_out, int out_size, void* d_ws, size_t ws_size,
                              hipStream_t stream) {
    const float* x = (const float*)d_in[0];
    const int total = in_sizes[0];          // B*T*C
    const int nrows = total / C_LEN;        // B*T
    const int B     = nrows / T_LEN;

    float* conf = (float*)d_ws;                                        // nrows f32
    int*   pred = (int*)((char*)d_ws + (size_t)nrows * sizeof(float)); // nrows i32
    float* out  = (float*)d_out;

    const int gridA = (nrows + 15) / 16;    // 16 rows per 256-thread block
    softmax_stats_kernel<<<gridA, 256, 0, stream>>>(x, conf, pred, nrows);
    // DIAGNOSTIC round 3: B launched 4x (idempotent). R1/R2 identity gives
    // OH + B = 326.4 us, A = 45.8 us. dur_us here = 372.2 + 3*B:
    //   B ~ 10 us -> ~400 us (OH ~316: harness poison/restore dominates ->
    //                         we are ~4% from floor; declare roofline next)
    //   B ~ 86 us -> ~630 us (B is the target; rewrite next round)
    topk_kernel<<<B, 256, 0, stream>>>(conf, pred, out);
    topk_kernel<<<B, 256, 0, stream>>>(conf, pred, out);
    topk_kernel<<<B, 256, 0, stream>>>(conf, pred, out);
    topk_kernel<<<B, 256, 0, stream>>>(conf, pred, out);
}

// Round 4
// 354.481 us; speedup vs baseline: 1.2262x; 1.2262x over previous
//
#include <hip/hip_runtime.h>
#include <stdint.h>

#define T_LEN 8192
#define C_LEN 64
#define OUT_LEN 8
#define SEG 2048      // T_LEN / 4 segments per sample
#define HALO 512      // run-probe halo; global fallback guarantees correctness

// ---------------------------------------------------------------------------
// Kernel A: per row (b,t): pred = argmax_c x[b,t,c] (ties -> lowest c),
// conf = max softmax = 1 / sum_c exp(x - max). 16 lanes/row, float4/lane.
// Measured R2: 45.8 us vs 42 us BW floor (264 MB @ 6.3 TB/s) -> ~91%.
// R4 change: single packed int2 store {conf_bits, pred} per row.
// ---------------------------------------------------------------------------
__global__ __launch_bounds__(256) void softmax_stats_kernel(
    const float* __restrict__ x, int2* __restrict__ packed, int nrows)
{
    const int tid  = threadIdx.x;
    const int wave = tid >> 6;
    const int lane = tid & 63;
    const int rw   = lane >> 4;   // row-within-wave (0..3)
    const int sub  = lane & 15;   // 16 lanes per row
    const long long row = (long long)blockIdx.x * 16 + wave * 4 + rw;
    if (row >= nrows) return;

    const float4 v = ((const float4*)(x + row * C_LEN))[sub];

    float m = v.x; int mi = sub * 4;
    if (v.y > m) { m = v.y; mi = sub * 4 + 1; }
    if (v.z > m) { m = v.z; mi = sub * 4 + 2; }
    if (v.w > m) { m = v.w; mi = sub * 4 + 3; }

    // sign-corrected monotone float-bits key | ~idx (tie -> lowest idx)
    const unsigned int s0 = __float_as_uint(m);
    const unsigned int u0 = (s0 & 0x80000000u) ? ~s0 : (s0 | 0x80000000u);
    unsigned long long key =
        ((unsigned long long)u0 << 32) | (unsigned int)~mi;

    #pragma unroll
    for (int off = 8; off >= 1; off >>= 1) {
        const unsigned long long o = __shfl_xor(key, off);
        if (o > key) key = o;
    }

    const unsigned int uu = (unsigned int)(key >> 32);
    const float M = __uint_as_float(
        (uu & 0x80000000u) ? (uu ^ 0x80000000u) : ~uu);

    float s = __expf(v.x - M) + __expf(v.y - M)
            + __expf(v.z - M) + __expf(v.w - M);
    #pragma unroll
    for (int off = 8; off >= 1; off >>= 1) s += __shfl_xor(s, off);

    if (sub == 0) {
        int2 o;
        o.x = __float_as_int(1.0f / s);
        o.y = (int)~(unsigned int)(key & 0xffffffffu);
        packed[row] = o;
    }
}

// ---------------------------------------------------------------------------
// Kernel B1: one block per (sample, segment-of-2048). RLE + voted conf,
// per-segment top-8 with removal -> 8 candidate keys to ws.
// Key = voted_float_bits<<32 | ~t_global: monotone for voted>=0, and ~t
// gives lax.top_k's lower-index tie-break; comparable across segments.
// ---------------------------------------------------------------------------
__global__ __launch_bounds__(256) void topk_seg_kernel(
    const int2* __restrict__ packed, unsigned long long* __restrict__ cand)
{
    __shared__ short pred_s[SEG + HALO + 1];  // [t-seg_start+1], idx 0 = t-1
    __shared__ float conf_s[SEG];
    __shared__ float voted_s[SEG];
    __shared__ unsigned long long wkey[4];
    __shared__ int dirty;                     // -1 all rescan, 0..3 wave, 4 none

    const int tid    = threadIdx.x;
    const int lane   = tid & 63, wave = tid >> 6;
    const int sample = blockIdx.x >> 2;
    const int seg    = blockIdx.x & 3;
    const int seg_start = seg * SEG;
    const int2* __restrict__ pp = packed + (long long)sample * T_LEN;

    const int lo = (seg == 0) ? 0 : seg_start - 1;
    int hi = seg_start + SEG + HALO; if (hi > T_LEN) hi = T_LEN;
    for (int i = lo + tid; i < hi; i += 256) {
        const int2 p = pp[i];
        pred_s[i - seg_start + 1] = (short)p.y;
        const int k = i - seg_start;
        if ((unsigned)k < SEG) conf_s[k] = __int_as_float(p.x);
    }
    if (seg == 0 && tid == 0) pred_s[0] = (short)0x7fff;  // t=0 always a start
    if (tid == 0) dirty = -1;
    __syncthreads();

    // voted = conf_at_start * run_len at run starts; 0 elsewhere
    // (real voted >= 1/64 > 0, so 0 marks both non-start and pad)
    for (int k = tid; k < SEG; k += 256) {
        const int t = seg_start + k;
        const short p = pred_s[k + 1];
        float v = 0.0f;
        if (p != pred_s[k]) {
            int len = 1;
            const int lim = hi - t;            // LDS-valid probe length
            while (len < lim && pred_s[k + 1 + len] == p) ++len;
            if (len == lim && t + len < T_LEN) {
                // ran off halo (P ~ (1/64)^511): finish from global
                while (t + len < T_LEN && (short)pp[t + len].y == p) ++len;
            }
            v = conf_s[k] * (float)len;
        }
        voted_s[k] = v;
    }
    __syncthreads();

    // 8 rounds of argmax-with-removal; only the wave that lost its winner
    // rescans its 512-elem quarter.
    for (int r = 0; r < OUT_LEN; ++r) {
        if (dirty == -1 || dirty == wave) {
            unsigned long long best = 0ull;
            const int base = wave * (SEG / 4);
            #pragma unroll
            for (int kk = 0; kk < SEG / 4 / 64; ++kk) {   // 8 iters
                const int k = base + kk * 64 + lane;
                const unsigned long long key =
                    ((unsigned long long)__float_as_uint(voted_s[k]) << 32)
                    | (unsigned int)~(seg_start + k);
                if (key > best) best = key;
            }
            #pragma unroll
            for (int off = 32; off >= 1; off >>= 1) {
                const unsigned long long o = __shfl_xor(best, off);
                if (o > best) best = o;
            }
            if (lane == 0) wkey[wave] = best;
        }
        __syncthreads();
        if (tid == 0) {
            unsigned long long bb = wkey[0];
            #pragma unroll
            for (int w = 1; w < 4; ++w) if (wkey[w] > bb) bb = wkey[w];
            if ((bb >> 32) != 0ull) {           // voted > 0
                const int tg = (int)~(unsigned int)(bb & 0xffffffffu);
                const int k = tg - seg_start;
                voted_s[k] = 0.0f;
                dirty = k / (SEG / 4);
            } else {
                dirty = 4;
            }
            cand[(long long)blockIdx.x * OUT_LEN + r] = bb;  // 0 = pad
        }
        __syncthreads();
    }
}

// ---------------------------------------------------------------------------
// Kernel B2: one wave per sample. Merge 4 segments x 8 candidates -> top-8
// in rank order. Global top-8 == top-8 of union of segment top-8s.
// ---------------------------------------------------------------------------
__global__ __launch_bounds__(64) void topk_merge_kernel(
    const unsigned long long* __restrict__ cand,
    const int2* __restrict__ packed, float* __restrict__ out)
{
    const int sample = blockIdx.x;
    const int lane   = threadIdx.x;

    unsigned long long key = 0ull;
    float pv = 0.0f;
    if (lane < 4 * OUT_LEN) key = cand[(long long)sample * 32 + lane];
    if (key != 0ull) {   // prefetch winner payload (pred value)
        const int tg = (int)~(unsigned int)(key & 0xffffffffu);
        pv = (float)packed[(long long)sample * T_LEN + tg].y;
    }

    for (int r = 0; r < OUT_LEN; ++r) {
        unsigned long long best = key;
        #pragma unroll
        for (int off = 32; off >= 1; off >>= 1) {
            const unsigned long long o = __shfl_xor(best, off);
            if (o > best) best = o;
        }
        if (best == 0ull) {                     // pad-with-0 path
            if (lane == 0) out[sample * OUT_LEN + r] = 0.0f;
        } else if (key == best) {               // unique: nonzero keys distinct
            out[sample * OUT_LEN + r] = pv;
            key = 0ull;
        }
    }
}

extern "C" void kernel_launch(void* const* d_in, const int* in_sizes, int n_in,
                              void* d_out, int out_size, void* d_ws, size_t ws_size,
                              hipStream_t stream) {
    const float* x  = (const float*)d_in[0];
    const int total = in_sizes[0];          // B*T*C
    const int nrows = total / C_LEN;        // B*T
    const int B     = nrows / T_LEN;

    int2* packed = (int2*)d_ws;                                   // nrows * 8B
    unsigned long long* cand =
        (unsigned long long*)((char*)d_ws + (size_t)nrows * sizeof(int2));
    float* out = (float*)d_out;

    const int gridA = (nrows + 15) / 16;    // 16 rows per 256-thread block
    softmax_stats_kernel<<<gridA, 256, 0, stream>>>(x, packed, nrows);
    topk_seg_kernel<<<B * 4, 256, 0, stream>>>(packed, cand);
    topk_merge_kernel<<<B, 64, 0, stream>>>(cand, packed, out);
}